// Round 4
// baseline (513.406 us; speedup 1.0000x reference)
//
#include <hip/hip_runtime.h>

#define TPB   256
#define WPB   (TPB / 64)       // 4 waves per block
#define WTILE 64               // batches per wave-phase: 64 * 96 B = 6 KB
#define GRAN  (WTILE * 7)      // 448 padded granules per wave tile (7168 B)
#define NB    2048             // 8192 waves; 65536 wave-tiles / 8192 = 8 phases exactly

typedef float f32x4 __attribute__((ext_vector_type(4)));

// Wave-private LDS tile, stride-7 granules (6 data + 1 pad per batch = 112 B).
// Read side: lane t reads granules 7t+j -> quad (j - t) mod 8, exactly 8 lanes
// per bank-quad -> conflict-free ds_read_b128.
// Write side: granule (f/6)*7 + f%6 -> quad (s - b) mod 8, <=2-way (free, m136).
// No __syncthreads in the hot loop: all LDS RAW/WAR hazards are same-wave,
// ordered by compiler-emitted s_waitcnt lgkmcnt.

__device__ __forceinline__ float group_loss(f32x4 a, f32x4 b, f32x4 c) {
    // vectors are (y,z,w) of each float4 (column 0 dropped)
    const float n0 = a.y * a.y + a.z * a.z + a.w * a.w;
    const float n1 = b.y * b.y + b.z * b.z + b.w * b.w;
    const float n2 = c.y * c.y + c.z * c.z + c.w * c.w;
    const float p01 = a.y * b.y + a.z * b.z + a.w * b.w;
    const float p02 = a.y * c.y + a.z * c.z + a.w * c.w;
    const float p12 = b.y * c.y + b.z * c.z + b.w * c.w;
    const float r0 = rsqrtf(n0), r1 = rsqrtf(n1), r2 = rsqrtf(n2);
    const float d01 = p01 * r0 * r1;
    const float d02 = p02 * r0 * r2;
    const float d12 = p12 * r1 * r2;
    // diagonal terms <u_i,u_i> - 1 are ~0 in fp32; contribute ~1e-14 to the mean. Skip.
    return 2.f * (d01 * d01 + d02 * d02 + d12 * d12);
}

__global__ __launch_bounds__(TPB, 4) void reg_loss_k1(
    const f32x4* __restrict__ in, float* __restrict__ partial, int B)
{
    __shared__ f32x4 tile[WPB][GRAN];   // 28 KB -> 5 blocks/CU = 20 waves/CU
    __shared__ float wsum[WPB];
    const int t    = threadIdx.x;
    const int lane = t & 63;
    const int wid  = t >> 6;

    const int nTiles = B / WTILE;
    const int nWaves = gridDim.x * WPB;

    f32x4* __restrict__ wt = tile[wid];

    // write-side granule addresses for this lane's 6 coalesced float4s
    int wa[6];
    #pragma unroll
    for (int k = 0; k < 6; ++k) {
        const int f = k * 64 + lane;
        const int b = f / 6;               // const-div -> magic mul
        wa[k] = b * 7 + (f - b * 6);
    }
    const int ro = lane * 7;               // lane owns batch `lane` of its tile

    float acc = 0.f;

    int tb = blockIdx.x * WPB + wid;
    f32x4 va[6], vb[6];
    if (tb < nTiles) {
        const f32x4* s = in + (size_t)tb * (WTILE * 6);
        #pragma unroll
        for (int k = 0; k < 6; ++k) va[k] = s[k * 64 + lane];
    }

    while (tb < nTiles) {
        // ---- phase A: stage va, prefetch vb, compute ----
        #pragma unroll
        for (int k = 0; k < 6; ++k) wt[wa[k]] = va[k];
        const int tn = tb + nWaves;
        if (tn < nTiles) {
            const f32x4* s = in + (size_t)tn * (WTILE * 6);
            #pragma unroll
            for (int k = 0; k < 6; ++k) vb[k] = s[k * 64 + lane];
        }
        acc += group_loss(wt[ro + 0], wt[ro + 1], wt[ro + 2]);
        acc += group_loss(wt[ro + 3], wt[ro + 4], wt[ro + 5]);

        if (tn >= nTiles) break;

        // ---- phase B: stage vb, prefetch va, compute ----
        #pragma unroll
        for (int k = 0; k < 6; ++k) wt[wa[k]] = vb[k];
        tb = tn + nWaves;
        if (tb < nTiles) {
            const f32x4* s = in + (size_t)tb * (WTILE * 6);
            #pragma unroll
            for (int k = 0; k < 6; ++k) va[k] = s[k * 64 + lane];
        }
        acc += group_loss(wt[ro + 0], wt[ro + 1], wt[ro + 2]);
        acc += group_loss(wt[ro + 3], wt[ro + 4], wt[ro + 5]);
    }

    // tail (B % WTILE != 0) — direct loads, block 0 only (dead at B = 4.19e6)
    if (blockIdx.x == 0) {
        for (int b = (B / WTILE) * WTILE + t; b < B; b += TPB) {
            const f32x4* p = in + (size_t)b * 6;
            acc += group_loss(p[0], p[1], p[2]);
            acc += group_loss(p[3], p[4], p[5]);
        }
    }

    // wave (64-lane) reduce, then cross-wave via LDS (single sync, cold path)
    for (int off = 32; off > 0; off >>= 1)
        acc += __shfl_down(acc, off, 64);
    if (lane == 0) wsum[wid] = acc;
    __syncthreads();
    if (t == 0) {
        float s = 0.f;
        #pragma unroll
        for (int w2 = 0; w2 < WPB; ++w2) s += wsum[w2];
        partial[blockIdx.x] = s;
    }
}

// Reduce partials -> mean (double accumulation, single block).
__global__ __launch_bounds__(TPB) void reg_loss_k2(
    const float* __restrict__ partial, float* __restrict__ out, int n, int B)
{
    __shared__ double wsum[TPB / 64];
    const int t = threadIdx.x;
    double s = 0.0;
    for (int i = t; i < n; i += TPB) s += (double)partial[i];
    for (int off = 32; off > 0; off >>= 1)
        s += __shfl_down(s, off, 64);
    if ((t & 63) == 0) wsum[t >> 6] = s;
    __syncthreads();
    if (t == 0) {
        double tot = 0.0;
        #pragma unroll
        for (int w = 0; w < TPB / 64; ++w) tot += wsum[w];
        out[0] = (float)(tot / (double)B);
    }
}

extern "C" void kernel_launch(void* const* d_in, const int* in_sizes, int n_in,
                              void* d_out, int out_size, void* d_ws, size_t ws_size,
                              hipStream_t stream) {
    const f32x4* in = (const f32x4*)d_in[0];
    const int B = in_sizes[0] / 24;            // (B, 6, 4) fp32
    float* partial = (float*)d_ws;

    int nb = NB;
    if ((size_t)nb * sizeof(float) > ws_size)
        nb = (int)(ws_size / sizeof(float));
    if (nb < 1) nb = 1;

    reg_loss_k1<<<nb, TPB, 0, stream>>>(in, partial, B);
    reg_loss_k2<<<1, TPB, 0, stream>>>(partial, (float*)d_out, nb, B);
}